// Round 17
// baseline (138.204 us; speedup 1.0000x reference)
//
#include <hip/hip_runtime.h>

#define RANK  32
#define DIM   128
#define TROWS 64   // rows per wave-task = 4 MFMA tile-rows

// Round-17 = round-15 pipeline x round-13 float4 stores: vmcnt decoupling.
// Issue accounting (r16 post-mortem): SIMDs ~97% idle — pure memory-wait.
// Mechanism: loads and stores share vmcnt. With 128 scalar stores/task the
// load-wait at cvt needs vmcnt(128) — inexpressible (max 63) — so every
// task the wave drains ~half its store acks under a 410MB write stream.
// With 32 dwordx4 stores/task (swapped-operand MFMA, HW-verified r13) and
// gathers issued BEFORE stores (r15 order), the load-wait is vmcnt(~33):
// expressible, stores stay in flight across task boundaries. Segment count
// is unchanged (r13 lesson) — the lever is wait semantics, not traffic.
// Layouts (m89/m162-verified, HW-confirmed r12-r16): A[m][k],B[k][n]:
// lane l elem e <-> m|n=l&15, k=4*(l>>4)+(e&3)+16*(e>>2).
// Swapped C: lane l reg rr = out[16tr+mn][16tc+4q+rr] -> float4 store.

typedef __attribute__((ext_vector_type(8))) short bf16x8;
typedef __attribute__((ext_vector_type(4))) float f32x4;

static __device__ __forceinline__ short f2bf(float f) {
  unsigned u = __float_as_uint(f);
  return (short)((u + 0x7FFFu + ((u >> 16) & 1u)) >> 16);  // RNE
}

__global__ __launch_bounds__(256)
__attribute__((amdgpu_waves_per_eu(4, 4)))
void lowrank_emb_kernel(
    const int* __restrict__ idx,
    const float* __restrict__ W1,
    const float* __restrict__ W2,
    float* __restrict__ out,
    int n_rows)
{
  const int lane       = threadIdx.x & 63;
  const int globalWave = blockIdx.x * 4 + (threadIdx.x >> 6);
  const int totalWaves = gridDim.x * 4;

  const int q   = lane >> 4;   // k-quad selector (0..3)
  const int mn  = lane & 15;   // row-of-A / col-of-B within tile
  const int nTasks  = (n_rows + TROWS - 1) / TROWS;
  const int lastIdx = n_rows - 1;

  int t = globalWave;
  if (t >= nTasks) return;

  // W2 fragments (A operand after the swap): lane l elem e holds
  // bf16(W2[4q+(e&3)+16*(e>>2)][16t+mn]). 32 VGPRs, pinned resident.
  bf16x8 bfrag[8];
#pragma unroll
  for (int tt = 0; tt < 8; ++tt) {
    bf16x8 v;
#pragma unroll
    for (int e = 0; e < 8; ++e) {
      const int k = 4 * q + (e & 3) + 16 * (e >> 2);
      v[e] = f2bf(W2[k * DIM + 16 * tt + mn]);
    }
    bfrag[tt] = v;
  }
#pragma unroll
  for (int tt = 0; tt < 8; ++tt) asm("" : "+v"(bfrag[tt]));

  auto gather = [&](int iv, float4* lo, float4* hi) {
    // Tile-row tr needs W1 row 16tr+mn, k-chunks [4q,+4) and [16+4q,+4).
    // 8 independent 16B loads; each W1 row fetched exactly once per task.
#pragma unroll
    for (int tr = 0; tr < 4; ++tr) {
      const int e = __shfl(iv, tr * 16 + mn, 64);
      const float* rp = W1 + (size_t)e * RANK + 4 * q;
      lo[tr] = *reinterpret_cast<const float4*>(rp);
      hi[tr] = *reinterpret_cast<const float4*>(rp + 16);
    }
  };

  // Prologue: idx + gathers for task t; idx prefetch for t+stride.
  float4 alo[4], ahi[4];
  {
    const int r = t * TROWS + lane;
    const int iv0 = idx[r < n_rows ? r : lastIdx];
    gather(iv0, alo, ahi);
  }
  int ivNext;
  {
    const int tn = t + totalWaves;
    const int r  = tn * TROWS + lane;
    ivNext = idx[(tn < nTasks && r < n_rows) ? r : lastIdx];
  }

  while (true) {
    // (1) Convert current task's gather to fragments (compiler's counted
    // vmcnt wait lands here — with only 32 stores outstanding it is
    // expressible and store acks are NOT drained).
    bf16x8 af[4];
#pragma unroll
    for (int tr = 0; tr < 4; ++tr) {
      bf16x8 v;
      v[0] = f2bf(alo[tr].x); v[1] = f2bf(alo[tr].y);
      v[2] = f2bf(alo[tr].z); v[3] = f2bf(alo[tr].w);
      v[4] = f2bf(ahi[tr].x); v[5] = f2bf(ahi[tr].y);
      v[6] = f2bf(ahi[tr].z); v[7] = f2bf(ahi[tr].w);
      af[tr] = v;
    }

    // (2) Issue NEXT task's gathers — BEFORE this task's stores, so the
    // loads sit ahead of the stores in the vmcnt queue.
    const int tn = t + totalWaves;
    if (tn < nTasks) gather(ivNext, alo, ahi);

    // (3) Prefetch idx two tasks ahead.
    {
      const int t2 = tn + totalWaves;
      const int r  = t2 * TROWS + lane;
      ivNext = idx[(t2 < nTasks && r < n_rows) ? r : lastIdx];
    }

    // (4) Swapped compute + float4 stores (32 store instrs per task):
    // acc[tc] reg rr = out[rowBase+16tr+mn][16tc+4q+rr].
    const int rowBase = t * TROWS;
    const bool full = (rowBase + TROWS) <= n_rows;
#pragma unroll
    for (int tr = 0; tr < 4; ++tr) {
      f32x4 acc[8];
#pragma unroll
      for (int tc = 0; tc < 8; ++tc)
        acc[tc] = __builtin_amdgcn_mfma_f32_16x16x32_bf16(
            bfrag[tc], af[tr], (f32x4){0.f, 0.f, 0.f, 0.f}, 0, 0, 0);

      const int orow = rowBase + tr * 16 + mn;
      float* op = out + (size_t)orow * DIM + 4 * q;
      if (full || orow < n_rows) {
#pragma unroll
        for (int tc = 0; tc < 8; ++tc)
          *reinterpret_cast<float4*>(op + 16 * tc) =
              make_float4(acc[tc][0], acc[tc][1], acc[tc][2], acc[tc][3]);
      }
    }

    if (tn >= nTasks) break;
    t = tn;
  }
}

extern "C" void kernel_launch(void* const* d_in, const int* in_sizes, int n_in,
                              void* d_out, int out_size, void* d_ws, size_t ws_size,
                              hipStream_t stream) {
  const int*   idx = (const int*)d_in[0];   // [4096*200]
  const float* W1  = (const float*)d_in[1]; // [1e6, 32]
  const float* W2  = (const float*)d_in[2]; // [32, 128]
  float*       out = (float*)d_out;         // [4096*200, 128]
  const int n_rows = in_sizes[0];

  const int threads = 256;   // 4 waves/block
  const int blocks  = 1024;  // exactly resident (4 blocks/CU); persistent loop
  hipLaunchKernelGGL(lowrank_emb_kernel, dim3(blocks), dim3(threads), 0, stream,
                     idx, W1, W2, out, n_rows);
}

// Round 18
// 125.417 us; speedup vs baseline: 1.1020x; 1.1020x over previous
//
#include <hip/hip_runtime.h>

#define RANK  32
#define DIM   128
#define TROWS 64   // rows per wave-task = 4 MFMA tile-rows

// Round-18: REVERT to round 15 verbatim (126.06us, session best).
// Round-17 falsified the vmcnt-decoupling theory: float4 stores cost +12us
// pipelined (r17) and +21us unpipelined (r13) — the wide store's 16
// scattered 64B segments per instruction lose at the TA/address level;
// scalar stores (4 segments/instr) are strictly better for this pattern.
// Axes now exhausted with null/negative results: store shape (r13/r17),
// NT stores (r16), pipeline depth (r14/r15), occupancy classes (r4-r11),
// LDS staging (r3-r11), MFMA operand order (r12/r13). Residual vs the
// ~85us naive floor is mixed-stream DRAM efficiency (random 64-128B reads
// interleaved with a 410MB streaming write), not source-addressable.
// Layouts (m89/m162-verified, HW-confirmed r12-r17):
// A[m][k],B[k][n]: lane l elem e <-> m|n=l&15, k=4*(l>>4)+(e&3)+16*(e>>2).
// C: row=(l>>4)*4+reg, col=l&15.

typedef __attribute__((ext_vector_type(8))) short bf16x8;
typedef __attribute__((ext_vector_type(4))) float f32x4;

static __device__ __forceinline__ short f2bf(float f) {
  unsigned u = __float_as_uint(f);
  return (short)((u + 0x7FFFu + ((u >> 16) & 1u)) >> 16);  // RNE
}

__global__ __launch_bounds__(256)
__attribute__((amdgpu_waves_per_eu(4, 4)))
void lowrank_emb_kernel(
    const int* __restrict__ idx,
    const float* __restrict__ W1,
    const float* __restrict__ W2,
    float* __restrict__ out,
    int n_rows)
{
  const int lane       = threadIdx.x & 63;
  const int globalWave = blockIdx.x * 4 + (threadIdx.x >> 6);
  const int totalWaves = gridDim.x * 4;

  const int q   = lane >> 4;   // k-quad selector (0..3)
  const int mn  = lane & 15;   // row-of-A / col-of-B within tile
  const int nTasks  = (n_rows + TROWS - 1) / TROWS;
  const int lastIdx = n_rows - 1;

  int t = globalWave;
  if (t >= nTasks) return;

  // W2 B-fragments: lane l elem e holds bf16(W2[4q+(e&3)+16*(e>>2)][16t+mn]).
  // 32 VGPRs, pinned resident (round-1 lesson).
  bf16x8 bfrag[8];
#pragma unroll
  for (int tt = 0; tt < 8; ++tt) {
    bf16x8 v;
#pragma unroll
    for (int e = 0; e < 8; ++e) {
      const int k = 4 * q + (e & 3) + 16 * (e >> 2);
      v[e] = f2bf(W2[k * DIM + 16 * tt + mn]);
    }
    bfrag[tt] = v;
  }
#pragma unroll
  for (int tt = 0; tt < 8; ++tt) asm("" : "+v"(bfrag[tt]));

  auto gather = [&](int iv, float4* lo, float4* hi) {
    // Tile-row tr needs W1 row 16tr+mn, k-chunks [4q,+4) and [16+4q,+4).
    // 8 independent 16B loads; each W1 row fetched exactly once per task.
#pragma unroll
    for (int tr = 0; tr < 4; ++tr) {
      const int e = __shfl(iv, tr * 16 + mn, 64);
      const float* rp = W1 + (size_t)e * RANK + 4 * q;
      lo[tr] = *reinterpret_cast<const float4*>(rp);
      hi[tr] = *reinterpret_cast<const float4*>(rp + 16);
    }
  };

  // Prologue: idx + gathers for task t; idx prefetch for t+stride.
  float4 alo[4], ahi[4];
  {
    const int r = t * TROWS + lane;
    const int iv0 = idx[r < n_rows ? r : lastIdx];
    gather(iv0, alo, ahi);
  }
  int ivNext;
  {
    const int tn = t + totalWaves;
    const int r  = tn * TROWS + lane;
    ivNext = idx[(tn < nTasks && r < n_rows) ? r : lastIdx];
  }

  while (true) {
    // (1) Convert current task's gather (compiler waits vmcnt here) to
    // fragments, freeing alo/ahi registers for the next task's loads.
    bf16x8 af[4];
#pragma unroll
    for (int tr = 0; tr < 4; ++tr) {
      bf16x8 v;
      v[0] = f2bf(alo[tr].x); v[1] = f2bf(alo[tr].y);
      v[2] = f2bf(alo[tr].z); v[3] = f2bf(alo[tr].w);
      v[4] = f2bf(ahi[tr].x); v[5] = f2bf(ahi[tr].y);
      v[6] = f2bf(ahi[tr].z); v[7] = f2bf(ahi[tr].w);
      af[tr] = v;
    }

    // (2) Issue NEXT task's gathers now — they fly under this task's
    // MFMA + stores (steady-state overlap).
    const int tn = t + totalWaves;
    if (tn < nTasks) gather(ivNext, alo, ahi);

    // (3) Prefetch idx two tasks ahead (lands long before its gather).
    {
      const int t2 = tn + totalWaves;
      const int r  = t2 * TROWS + lane;
      ivNext = idx[(t2 < nTasks && r < n_rows) ? r : lastIdx];
    }

    // (4) Compute + store current task (proven scalar-store path).
    const int rowBase = t * TROWS;
    const bool full = (rowBase + TROWS) <= n_rows;
#pragma unroll
    for (int tr = 0; tr < 4; ++tr) {
      f32x4 acc[8];
#pragma unroll
      for (int tc = 0; tc < 8; ++tc)
        acc[tc] = __builtin_amdgcn_mfma_f32_16x16x32_bf16(
            af[tr], bfrag[tc], (f32x4){0.f, 0.f, 0.f, 0.f}, 0, 0, 0);

      const int rb = rowBase + tr * 16 + q * 4;  // C: row=(l>>4)*4+reg
#pragma unroll
      for (int rr = 0; rr < 4; ++rr) {
        if (full || (rb + rr) < n_rows) {
          float* op = out + (size_t)(rb + rr) * DIM + mn;
#pragma unroll
          for (int tc = 0; tc < 8; ++tc) op[16 * tc] = acc[tc][rr];
        }
      }
    }

    if (tn >= nTasks) break;
    t = tn;
  }
}

extern "C" void kernel_launch(void* const* d_in, const int* in_sizes, int n_in,
                              void* d_out, int out_size, void* d_ws, size_t ws_size,
                              hipStream_t stream) {
  const int*   idx = (const int*)d_in[0];   // [4096*200]
  const float* W1  = (const float*)d_in[1]; // [1e6, 32]
  const float* W2  = (const float*)d_in[2]; // [32, 128]
  float*       out = (float*)d_out;         // [4096*200, 128]
  const int n_rows = in_sizes[0];

  const int threads = 256;   // 4 waves/block
  const int blocks  = 1024;  // exactly resident (4 blocks/CU); persistent loop
  hipLaunchKernelGGL(lowrank_emb_kernel, dim3(blocks), dim3(threads), 0, stream,
                     idx, W1, W2, out, n_rows);
}